// Round 10
// baseline (27.917 us; speedup 1.0000x reference)
//
#include <hip/hip_runtime.h>

#define SN 128
#define SPK 512

constexpr float GMIN  = 0.1f;
constexpr float PFRAC = 0.3f;
constexpr float GMAX  = 1.0f;

// Wave-synchronous lazy-decay kernel, 32 cells/lane, LDS-compacted event list.
// Block = one 64-lane wave = (s, p, xq): x in [xq*16, xq*16+16), all 128 y.
// Lane: xp = lane>>3 (x-pair), yb = lane&7 (16-wide y chunk).
// Cells: a[j], j = (x&1)<<4 | (y&15);  v = C(n)*a + GMIN, C(n)=exp((ts0-ts[n])/TAU).
// Spike: a' = (1-PFRAC)*a + PFRAC*(GMAX-GMIN)/C(n).
// Phase A: ballot-compact {owner events, surviving snapshots} into LDS (time order).
// Phase B: single loop over the list; broadcast ds_read_b128, scalar dispatch.
//
// meta: bits 4-14 pos (p<<14|x<<7|y masked 0x7F70) | bit 15 owner-valid |
//       bits 16-20 jidx | bits 24-26 tt value | bit 31 snapshot flag.

__global__ __launch_bounds__(64, 2) void trace_kernel(
    const int*   __restrict__ event,   // (SN, SPK, 3) int32: x, y, pol
    const float* __restrict__ ts,      // (SN, SPK) f32, ascending
    const int*   __restrict__ tt,      // (SN, SPK) int32 in [0,8)
    const int*   __restrict__ length,  // (SN,) int32
    float*       __restrict__ out)     // (SN, 8, 2, 64, 64) f32
{
    __shared__ uint4 sent[SPK + 10];   // worst case 511 owners + 8 snaps + 2 pads

    const int wg   = blockIdx.x;
    const int s    = wg >> 4;
    const int p    = (wg >> 3) & 1;
    const int xq   = wg & 7;
    const int lane = threadIdx.x;      // 0..63

    const int   len = length[s];
    const float ts0 = ts[s * SPK];

    // ---- pass 1: load + pack per-step state (16 regs) ----
    unsigned meta[8]; float tsn[8];
#pragma unroll
    for (int r8 = 0; r8 < 8; ++r8) {
        int n = r8 * 64 + lane;
        int tv_ = tt[s * SPK + n];
        tsn[r8] = ts[s * SPK + n];
        const int* ev = event + (size_t)(s * SPK + n) * 3;
        int ex = ev[0], ey = ev[1], ep = ev[2];
        unsigned mw = (unsigned)tv_ << 24;
        bool ownerb = (n >= 1) && (n < len) && (ep == p) && ((ex >> 4) == xq);
        if (ownerb) {
            mw |= 0x8000u
                | ((unsigned)((p << 14) | (ex << 7) | ey) & 0x7F70u)
                | ((unsigned)(((ex & 1) << 4) | (ey & 15)) << 16);
        }
        meta[r8] = mw;
    }

    // ---- snlast per slot: reverse scan with uniform early-exit ----
    int snl[8];
#pragma unroll
    for (int r = 0; r < 8; ++r) {
        int f = -1;
#pragma unroll
        for (int rr = 7; rr >= 0; --rr) {
            if (f < 0) {   // wave-uniform guard: skip ballots once found
                unsigned long long m =
                    __ballot(((meta[rr] >> 24) & 7u) == (unsigned)r &&
                             (rr > 0 || lane > 0));
                if (m) f = rr * 64 + 63 - __clzll(m);
            }
        }
        snl[r] = f;
    }

    // ---- phase A: ballot-compaction of survivors into LDS ----
    const unsigned long long lmask = (1ull << lane) - 1ull;
    int base = 0;
#pragma unroll
    for (int r8 = 0; r8 < 8; ++r8) {
        int n = r8 * 64 + lane;
        unsigned mw = meta[r8];
        bool psnap = false;
#pragma unroll
        for (int r = 0; r < 8; ++r) psnap |= (n == snl[r]);
        bool pred = psnap || ((mw >> 15) & 1u);

        unsigned long long bmask = __ballot(pred);
        if (pred) {
            float d  = (ts0 - tsn[r8]) * 0.01f;            // TAU = 100
            float C  = __expf(d);
            float Cr = (PFRAC * (GMAX - GMIN)) * __expf(-d);
            if (psnap) mw |= 0x80000000u;
            int idx = base + (int)__popcll(bmask & lmask);
            sent[idx] = make_uint4(mw, __float_as_uint(C), __float_as_uint(Cr), 0u);
        }
        base += (int)__popcll(bmask);
    }
    const int cnt = base;
    if (lane < 2) sent[cnt + lane] = make_uint4(0u, 0u, 0u, 0u);   // pads

    // ---- per-lane cell block ----
    const int xp     = lane >> 3;
    const int yb     = lane & 7;
    const int x_even = xq * 16 + 2 * xp;
    const unsigned mypat = (unsigned)((p << 14) | (x_even << 7) | (yb << 4));
    const int Xo = xq * 8 + xp;

    float a[32];
#pragma unroll
    for (int j = 0; j < 32; ++j) a[j] = -GMIN;             // v = 0 everywhere

    // init spike at n=0 (C(0)=1); uniform-address loads -> scalar
    bool own0 = false; int j0 = 0;
    {
        const int* ev0 = event + (size_t)s * SPK * 3;
        int x0 = ev0[0], y0 = ev0[1], p0 = ev0[2];
        unsigned pos0 = (unsigned)((p0 << 14) | (x0 << 7) | y0);
        if ((pos0 & 0x7F70u) == mypat) {
            own0 = true;
            j0 = ((x0 & 1) << 4) | (y0 & 15);
#pragma unroll
            for (int j = 0; j < 32; ++j)
                if (j == j0) a[j] = PFRAC * (GMAX - GMIN) - GMIN;
        }
    }

    // ---- phase B: single walk over the compacted list ----
    uint4 e0 = sent[0];
    uint4 e1 = sent[1];
    for (int i = 0; i < cnt; ++i) {
        uint4 e2 = sent[i + 2];
        unsigned mw = (unsigned)__builtin_amdgcn_readfirstlane((int)e0.x);

        if (mw & 0x8000u) {                 // owner event (scalar guard)
            float Crs  = __int_as_float(__builtin_amdgcn_readfirstlane((int)e0.z));
            bool  own  = (mw & 0x7F70u) == mypat;
            float coef = own ? (1.0f - PFRAC) : 1.0f;
            float addb = own ? Crs : 0.0f;
            switch ((mw >> 16) & 31u) {     // uniform jidx
#define OWN_CASE(k) case k: a[k] = fmaf(coef, a[k], addb); break;
                OWN_CASE(0)  OWN_CASE(1)  OWN_CASE(2)  OWN_CASE(3)
                OWN_CASE(4)  OWN_CASE(5)  OWN_CASE(6)  OWN_CASE(7)
                OWN_CASE(8)  OWN_CASE(9)  OWN_CASE(10) OWN_CASE(11)
                OWN_CASE(12) OWN_CASE(13) OWN_CASE(14) OWN_CASE(15)
                OWN_CASE(16) OWN_CASE(17) OWN_CASE(18) OWN_CASE(19)
                OWN_CASE(20) OWN_CASE(21) OWN_CASE(22) OWN_CASE(23)
                OWN_CASE(24) OWN_CASE(25) OWN_CASE(26) OWN_CASE(27)
                OWN_CASE(28) OWN_CASE(29) OWN_CASE(30) OWN_CASE(31)
#undef OWN_CASE
            }
        }

        if ((int)mw < 0) {                  // snapshot (scalar guard)
            float C  = __int_as_float(__builtin_amdgcn_readfirstlane((int)e0.y));
            int   rr = (int)((mw >> 24) & 7u);
            float o[8];
#pragma unroll
            for (int k = 0; k < 8; ++k) {
                float v0 = fmaf(C, a[2 * k],      GMIN);
                float v1 = fmaf(C, a[2 * k + 1],  GMIN);
                float v2 = fmaf(C, a[16 + 2 * k], GMIN);
                float v3 = fmaf(C, a[17 + 2 * k], GMIN);
                o[k] = fmaxf(fmaxf(fmaxf(v0, v1), v2), v3);   // max3 + max
            }
            float* dst = out +
                (size_t)((((s * 8 + rr) * 2 + p) * 64 + Xo) * 64 + yb * 8);
            *reinterpret_cast<float4*>(dst)     = make_float4(o[0], o[1], o[2], o[3]);
            *reinterpret_cast<float4*>(dst + 4) = make_float4(o[4], o[5], o[6], o[7]);
        }
        e0 = e1;
        e1 = e2;
    }

    // ---- slots that never occur at n>=1: default snapshots ----
#pragma unroll
    for (int r = 0; r < 8; ++r) {
        if (snl[r] < 0) {
            float o[8];
#pragma unroll
            for (int k = 0; k < 8; ++k) {
                bool hit = (r == 0) && own0 && (k == ((j0 & 15) >> 1));
                o[k] = hit ? PFRAC * (GMAX - GMIN) : 0.0f;
            }
            float* dst = out +
                (size_t)((((s * 8 + r) * 2 + p) * 64 + Xo) * 64 + yb * 8);
            *reinterpret_cast<float4*>(dst)     = make_float4(o[0], o[1], o[2], o[3]);
            *reinterpret_cast<float4*>(dst + 4) = make_float4(o[4], o[5], o[6], o[7]);
        }
    }
}

extern "C" void kernel_launch(void* const* d_in, const int* in_sizes, int n_in,
                              void* d_out, int out_size, void* d_ws, size_t ws_size,
                              hipStream_t stream) {
    const int*   event  = (const int*)  d_in[0];
    const float* ts     = (const float*)d_in[1];
    const int*   tt     = (const int*)  d_in[2];
    const int*   length = (const int*)  d_in[3];
    float*       out    = (float*)d_out;

    // 128 samples x 2 polarities x 8 x-chunks = 2048 one-wave blocks
    trace_kernel<<<dim3(SN * 2 * 8), dim3(64), 0, stream>>>(event, ts, tt, length, out);
}